// Round 1
// baseline (275083.374 us; speedup 1.0000x reference)
//
#include <hip/hip_runtime.h>
#include <math.h>

#define SEQ    8192
#define NSTEPS 2048
#define IDIM   256
#define HDIM   1024

#define NWG    256      // workgroups in cooperative grid
#define TPB    512      // threads per block = 8 waves
#define WPB    8        // waves per block

// ---- workspace layout (in floats) ----
// WT: packed transposed weights, 8 slots of [1024][1024]: slot(2i)=A_i cols, slot(2i+1)=B_i cols
//     A_0 = W_fused = out_W^T @ Wx0 ; A_i = Wx_rest[i-1] (i>=1) ; B_0 = Wh0 ; B_i = Wh_rest[i-1]
//     WT[slot][j][l] = M[l][j]  (column j contiguous over row index l -> coalesced lane loads)
#define WT_OFF   0ull
#define WT_SZ    (8ull*HDIM*HDIM)
#define WX0T_OFF (WT_OFF + WT_SZ)            // WX0T[j][l'] = Wx0[l'][j], 1024x256
#define WX0T_SZ  ((unsigned long long)HDIM*IDIM)
#define BF_OFF   (WX0T_OFF + WX0T_SZ)        // b_fused[1024]
#define OBUF_OFF (BF_OFF + HDIM)             // open-loop state, double-buffered [2][4][1024]
#define CBUF_OFF (OBUF_OFF + 8192ull)        // closed-loop state, double-buffered [2][4][1024]
#define BAR_OFF  (CBUF_OFF + 8192ull)        // barrier: cnt at [0], gen at [64] (different lines)

// ---------------- setup kernels ----------------

// WT slot 0 (transposed W_fused): WT0[j][l] = sum_k out_W[k][l] * Wx0[k][j]
__global__ void k_fuse_w(const float* __restrict__ outW, const float* __restrict__ Wx0,
                         float* __restrict__ ws) {
    int l = blockIdx.x * 256 + threadIdx.x;   // grid (4, 1024)
    int j = blockIdx.y;
    float acc = 0.f;
    for (int k = 0; k < IDIM; ++k)
        acc += outW[(size_t)k * HDIM + l] * Wx0[(size_t)k * HDIM + j];
    ws[WT_OFF + (size_t)j * HDIM + l] = acc;
}

// b_fused[j] = b0[j] + sum_k out_b[k] * Wx0[k][j]
__global__ void k_fuse_b(const float* __restrict__ b0, const float* __restrict__ outb,
                         const float* __restrict__ Wx0, float* __restrict__ ws) {
    int j = blockIdx.x * 256 + threadIdx.x;   // grid (4)
    float acc = b0[j];
    for (int k = 0; k < IDIM; ++k)
        acc += outb[k] * Wx0[(size_t)k * HDIM + j];
    ws[BF_OFF + j] = acc;
}

// transpose-pack the seven 1024x1024 matrices into WT slots 1..7
__global__ void k_pack(const float* __restrict__ Wh0, const float* __restrict__ Wxr,
                       const float* __restrict__ Whr, float* __restrict__ ws) {
    __shared__ float t[32][33];
    int z = blockIdx.z;
    const float* src; int slot;
    if (z == 0)      { src = Wh0;                                  slot = 1; }
    else if (z <= 3) { src = Wxr + (size_t)(z - 1) * HDIM * HDIM;  slot = 2 * z; }
    else             { src = Whr + (size_t)(z - 4) * HDIM * HDIM;  slot = 2 * (z - 4) + 3; }
    int j0 = blockIdx.x * 32, l0 = blockIdx.y * 32;
    t[threadIdx.y][threadIdx.x] = src[(size_t)(l0 + threadIdx.y) * HDIM + j0 + threadIdx.x];
    __syncthreads();
    float* dst = ws + WT_OFF + (size_t)slot * HDIM * HDIM;
    dst[(size_t)(j0 + threadIdx.y) * HDIM + (l0 + threadIdx.x)] = t[threadIdx.x][threadIdx.y];
}

// WX0T[j][l'] = Wx0[l'][j]  (256x1024 -> 1024x256)
__global__ void k_pack_wx0(const float* __restrict__ Wx0, float* __restrict__ ws) {
    __shared__ float t[32][33];
    int j0 = blockIdx.x * 32, l0 = blockIdx.y * 32;   // grid (32, 8)
    t[threadIdx.y][threadIdx.x] = Wx0[(size_t)(l0 + threadIdx.y) * HDIM + j0 + threadIdx.x];
    __syncthreads();
    ws[WX0T_OFF + (size_t)(j0 + threadIdx.y) * IDIM + (l0 + threadIdx.x)] = t[threadIdx.x][threadIdx.y];
}

// zero open-loop state buffers + barrier variables
__global__ void k_init(float* __restrict__ ws) {
    int t = blockIdx.x * blockDim.x + threadIdx.x;   // grid(16) x 512
    if (t < 8192) ws[OBUF_OFF + t] = 0.f;
    if (t == 0) {
        unsigned* b = (unsigned*)(ws + BAR_OFF);
        b[0] = 0u;   // cnt
        b[64] = 0u;  // gen
    }
}

// ---------------- scan kernel ----------------

__device__ __forceinline__ float wsum(float v) {
#pragma unroll
    for (int off = 32; off > 0; off >>= 1) v += __shfl_xor(v, off, 64);
    return v;
}

__device__ __forceinline__ void gbar(unsigned* cnt, unsigned* gen) {
    __syncthreads();
    if (threadIdx.x == 0) {
        __threadfence();  // release our h-writes device-wide
        unsigned g = __hip_atomic_load(gen, __ATOMIC_ACQUIRE, __HIP_MEMORY_SCOPE_AGENT);
        unsigned a = __hip_atomic_fetch_add(cnt, 1u, __ATOMIC_ACQ_REL, __HIP_MEMORY_SCOPE_AGENT);
        if (a == NWG - 1) {
            __hip_atomic_store(cnt, 0u, __ATOMIC_RELAXED, __HIP_MEMORY_SCOPE_AGENT);
            __hip_atomic_store(gen, g + 1u, __ATOMIC_RELEASE, __HIP_MEMORY_SCOPE_AGENT);
        } else {
            while (__hip_atomic_load(gen, __ATOMIC_RELAXED, __HIP_MEMORY_SCOPE_AGENT) == g)
                __builtin_amdgcn_s_sleep(1);
        }
        __threadfence();  // acquire: invalidate stale L1/L2 before consuming others' h
    }
    __syncthreads();
}

__global__ __launch_bounds__(TPB, 2) void k_scan(
    const float* __restrict__ xs, const float* __restrict__ b0,
    const float* __restrict__ brest, const float* __restrict__ outW,
    const float* __restrict__ outb, float* __restrict__ ws, float* __restrict__ out)
{
    const int lane  = threadIdx.x & 63;
    const int wv    = threadIdx.x >> 6;
    const int g     = blockIdx.x * WPB + wv;    // 0..2047
    const int layer = g >> 9;                   // 512 waves per layer
    const int jp    = g & 511;
    const int j0    = jp * 2;                   // this wave owns columns j0, j0+1

    const float* WX0T = ws + WX0T_OFF;
    const float* bfv  = ws + BF_OFF;
    float* obuf = ws + OBUF_OFF;
    float* cbuf = ws + CBUF_OFF;
    unsigned* cnt = (unsigned*)(ws + BAR_OFF);
    unsigned* gen = cnt + 64;

    // -- preload weight columns into VGPRs (coalesced; one-time) --
    float A0[16], A1[16], B0[16], B1[16];
    {
        const float* a = ws + ((size_t)(2 * layer) * HDIM + j0) * HDIM;
        const float* b = ws + ((size_t)(2 * layer + 1) * HDIM + j0) * HDIM;
#pragma unroll
        for (int k = 0; k < 16; ++k) {
            A0[k] = a[lane + 64 * k];  A1[k] = a[HDIM + lane + 64 * k];
            B0[k] = b[lane + 64 * k];  B1[k] = b[HDIM + lane + 64 * k];
        }
    }
    float wx0a[4] = {0,0,0,0}, wx0b[4] = {0,0,0,0};
    if (layer == 0) {
        const float* p = WX0T + (size_t)j0 * IDIM;
#pragma unroll
        for (int k = 0; k < 4; ++k) { wx0a[k] = p[lane + 64 * k]; wx0b[k] = p[IDIM + lane + 64 * k]; }
    }
    const bool outwave = (layer == 3) && (jp < IDIM);
    float ow[16]; float ob = 0.f;
    if (outwave) {
        const float* p = outW + (size_t)jp * HDIM;
#pragma unroll
        for (int k = 0; k < 16; ++k) ow[k] = p[lane + 64 * k];
        ob = outb[jp];
    }
    float bias0, bias1, bf0 = 0.f, bf1 = 0.f;
    if (layer == 0) { bias0 = b0[j0]; bias1 = b0[j0 + 1]; bf0 = bfv[j0]; bf1 = bfv[j0 + 1]; }
    else            { bias0 = brest[(layer - 1) * HDIM + j0]; bias1 = brest[(layer - 1) * HDIM + j0 + 1]; }

    float hl0 = 0.f, hl1 = 0.f;   // this wave's h at t = SEQ-1 (closed-loop init)

    // ---- PHASE 1: open loop, wavefront over layers (step s: layer i does t = s-i) ----
    for (int s = 0; s <= SEQ + 3; ++s) {
        const float* R  = obuf + (s & 1) * 4096;         // state written at step s-1
        float*       Wb = obuf + ((s + 1) & 1) * 4096;   // state for step s+1
        const int t = s - layer;
        if (t >= 0 && t < SEQ) {
            float acc0 = 0.f, acc1 = 0.f;
            if (layer == 0) {
                const float* xr = xs + (size_t)t * IDIM;
#pragma unroll
                for (int k = 0; k < 4; ++k) {
                    float x = xr[lane + 64 * k];
                    acc0 += x * wx0a[k]; acc1 += x * wx0b[k];
                }
            } else {
                const float* hin = R + (layer - 1) * HDIM;   // h_{layer-1}^t
#pragma unroll
                for (int k = 0; k < 16; ++k) {
                    float x = hin[lane + 64 * k];
                    acc0 += x * A0[k]; acc1 += x * A1[k];
                }
            }
            const float* hpr = R + layer * HDIM;             // h_layer^{t-1}
#pragma unroll
            for (int k = 0; k < 16; ++k) {
                float x = hpr[lane + 64 * k];
                acc0 += x * B0[k]; acc1 += x * B1[k];
            }
            acc0 = wsum(acc0); acc1 = wsum(acc1);
            float r0 = tanhf(acc0 + bias0);
            float r1 = tanhf(acc1 + bias1);
            if (lane == 0) {
                Wb[layer * HDIM + j0]     = r0;
                Wb[layer * HDIM + j0 + 1] = r1;
            }
            if (t == SEQ - 1) { hl0 = r0; hl1 = r1; }
        }
        // open-loop output rows: out[t'] = out_W @ h3^{t'} + out_b, t' = s-4
        if (outwave && s >= 4) {
            const float* h3 = R + 3 * HDIM;
            float acc = 0.f;
#pragma unroll
            for (int k = 0; k < 16; ++k) acc += h3[lane + 64 * k] * ow[k];
            acc = wsum(acc);
            if (lane == 0) out[(size_t)(s - 4) * IDIM + jp] = acc + ob;
        }
        gbar(cnt, gen);
    }

    // init closed-loop "prev" state (parity buffer 1) from registers
    if (lane == 0) {
        cbuf[4096 + layer * HDIM + j0]     = hl0;
        cbuf[4096 + layer * HDIM + j0 + 1] = hl1;
    }
    gbar(cnt, gen);

    // ---- PHASE 2: closed loop. Stage 0 fused: h0 = tanh(h3_prev@W_fused + h0_prev@Wh0 + b_fused)
    for (int t = 0; t < NSTEPS; ++t) {
        float*       cur  = cbuf + (t & 1) * 4096;
        const float* prev = cbuf + ((t + 1) & 1) * 4096;
        // stage 0 (layer-0 waves); idle layer-3 out-waves emit output row t-1
        if (layer == 0) {
            float acc0 = 0.f, acc1 = 0.f;
            const float* h3 = prev + 3 * HDIM;
            const float* h0 = prev;
#pragma unroll
            for (int k = 0; k < 16; ++k) {
                float x = h3[lane + 64 * k]; acc0 += x * A0[k]; acc1 += x * A1[k];
                float y = h0[lane + 64 * k]; acc0 += y * B0[k]; acc1 += y * B1[k];
            }
            acc0 = wsum(acc0); acc1 = wsum(acc1);
            float r0 = tanhf(acc0 + bf0);
            float r1 = tanhf(acc1 + bf1);
            if (lane == 0) { cur[j0] = r0; cur[j0 + 1] = r1; }
        } else if (outwave && t > 0) {
            const float* h3 = prev + 3 * HDIM;   // h3^{t-1}
            float acc = 0.f;
#pragma unroll
            for (int k = 0; k < 16; ++k) acc += h3[lane + 64 * k] * ow[k];
            acc = wsum(acc);
            if (lane == 0) out[(size_t)(SEQ + t - 1) * IDIM + jp] = acc + ob;
        }
        gbar(cnt, gen);
        // stages 1..3
        for (int i = 1; i < 4; ++i) {
            if (layer == i) {
                const float* hin = cur + (i - 1) * HDIM;   // h_{i-1}^t
                const float* hpr = prev + i * HDIM;        // h_i^{t-1}
                float acc0 = 0.f, acc1 = 0.f;
#pragma unroll
                for (int k = 0; k < 16; ++k) {
                    float x = hin[lane + 64 * k]; acc0 += x * A0[k]; acc1 += x * A1[k];
                    float y = hpr[lane + 64 * k]; acc0 += y * B0[k]; acc1 += y * B1[k];
                }
                acc0 = wsum(acc0); acc1 = wsum(acc1);
                float r0 = tanhf(acc0 + bias0);
                float r1 = tanhf(acc1 + bias1);
                if (lane == 0) { cur[i * HDIM + j0] = r0; cur[i * HDIM + j0 + 1] = r1; }
            }
            gbar(cnt, gen);
        }
    }
    // epilogue: final output row from h3^{NSTEPS-1}
    if (outwave) {
        const float* h3 = cbuf + ((NSTEPS - 1) & 1) * 4096 + 3 * HDIM;
        float acc = 0.f;
#pragma unroll
        for (int k = 0; k < 16; ++k) acc += h3[lane + 64 * k] * ow[k];
        acc = wsum(acc);
        if (lane == 0) out[(size_t)(SEQ + NSTEPS - 1) * IDIM + jp] = acc + ob;
    }
}

// ---------------- launcher ----------------

extern "C" void kernel_launch(void* const* d_in, const int* in_sizes, int n_in,
                              void* d_out, int out_size, void* d_ws, size_t ws_size,
                              hipStream_t stream) {
    (void)in_sizes; (void)n_in; (void)out_size; (void)ws_size;
    const float* xs   = (const float*)d_in[0];
    const float* Wx0  = (const float*)d_in[1];
    const float* Wh0  = (const float*)d_in[2];
    const float* b0   = (const float*)d_in[3];
    const float* Wxr  = (const float*)d_in[4];
    const float* Whr  = (const float*)d_in[5];
    const float* brst = (const float*)d_in[6];
    const float* outW = (const float*)d_in[7];
    const float* outb = (const float*)d_in[8];
    float* ws  = (float*)d_ws;
    float* out = (float*)d_out;

    k_fuse_w<<<dim3(4, HDIM), dim3(256), 0, stream>>>(outW, Wx0, ws);
    k_fuse_b<<<dim3(4), dim3(256), 0, stream>>>(b0, outb, Wx0, ws);
    k_pack<<<dim3(32, 32, 7), dim3(32, 32), 0, stream>>>(Wh0, Wxr, Whr, ws);
    k_pack_wx0<<<dim3(32, 8), dim3(32, 32), 0, stream>>>(Wx0, ws);
    k_init<<<dim3(16), dim3(512), 0, stream>>>(ws);

    void* args[] = { (void*)&xs, (void*)&b0, (void*)&brst, (void*)&outW,
                     (void*)&outb, (void*)&ws, (void*)&out };
    hipError_t e = hipLaunchCooperativeKernel((void*)k_scan, dim3(NWG), dim3(TPB),
                                              args, 0, stream);
    if (e != hipSuccess) {
        // fallback: plain launch (2048 waves on 256 CUs = 4x co-residency headroom)
        k_scan<<<dim3(NWG), dim3(TPB), 0, stream>>>(xs, b0, brst, outW, outb, ws, out);
    }
}

// Round 2
// 183468.591 us; speedup vs baseline: 1.4993x; 1.4993x over previous
//
#include <hip/hip_runtime.h>
#include <math.h>

#define SEQ    8192
#define NSTEPS 2048
#define IDIM   256
#define HDIM   1024

#define NWG    256      // workgroups in cooperative grid
#define TPB    512      // threads per block = 8 waves
#define WPB    8        // waves per block

// ---- workspace layout (in floats) ----
// WT: packed transposed weights, 8 slots of [1024][1024]: slot(2i)=A_i cols, slot(2i+1)=B_i cols
//     A_0 = W_fused = out_W^T @ Wx0 ; A_i = Wx_rest[i-1] (i>=1) ; B_0 = Wh0 ; B_i = Wh_rest[i-1]
//     WT[slot][j][l] = M[l][j]  (column j contiguous over row index l -> coalesced lane loads)
#define WT_OFF   0ull
#define WT_SZ    (8ull*HDIM*HDIM)
#define WX0T_OFF (WT_OFF + WT_SZ)            // WX0T[j][l'] = Wx0[l'][j], 1024x256
#define WX0T_SZ  ((unsigned long long)HDIM*IDIM)
#define BF_OFF   (WX0T_OFF + WX0T_SZ)        // b_fused[1024]
#define OBUF_OFF (BF_OFF + HDIM)             // open-loop state, double-buffered [2][4][1024]
#define CBUF_OFF (OBUF_OFF + 8192ull)        // closed-loop state, double-buffered [2][4][1024]

// ---- barrier state in device globals (zeroed by k_init every launch) ----
// flags[wg*16]: per-WG arrival flag, one 64B line per WG (no store serialization, no RMW)
// g_gen: generation word published by master (WG 0)
__device__ unsigned g_flags[4096];
__device__ unsigned g_gen;

// ---------------- setup kernels ----------------

// WT slot 0 (transposed W_fused): WT0[j][l] = sum_k out_W[k][l] * Wx0[k][j]
__global__ void k_fuse_w(const float* __restrict__ outW, const float* __restrict__ Wx0,
                         float* __restrict__ ws) {
    int l = blockIdx.x * 256 + threadIdx.x;   // grid (4, 1024)
    int j = blockIdx.y;
    float acc = 0.f;
    for (int k = 0; k < IDIM; ++k)
        acc += outW[(size_t)k * HDIM + l] * Wx0[(size_t)k * HDIM + j];
    ws[WT_OFF + (size_t)j * HDIM + l] = acc;
}

// b_fused[j] = b0[j] + sum_k out_b[k] * Wx0[k][j]
__global__ void k_fuse_b(const float* __restrict__ b0, const float* __restrict__ outb,
                         const float* __restrict__ Wx0, float* __restrict__ ws) {
    int j = blockIdx.x * 256 + threadIdx.x;   // grid (4)
    float acc = b0[j];
    for (int k = 0; k < IDIM; ++k)
        acc += outb[k] * Wx0[(size_t)k * HDIM + j];
    ws[BF_OFF + j] = acc;
}

// transpose-pack the seven 1024x1024 matrices into WT slots 1..7
__global__ void k_pack(const float* __restrict__ Wh0, const float* __restrict__ Wxr,
                       const float* __restrict__ Whr, float* __restrict__ ws) {
    __shared__ float t[32][33];
    int z = blockIdx.z;
    const float* src; int slot;
    if (z == 0)      { src = Wh0;                                  slot = 1; }
    else if (z <= 3) { src = Wxr + (size_t)(z - 1) * HDIM * HDIM;  slot = 2 * z; }
    else             { src = Whr + (size_t)(z - 4) * HDIM * HDIM;  slot = 2 * (z - 4) + 3; }
    int j0 = blockIdx.x * 32, l0 = blockIdx.y * 32;
    t[threadIdx.y][threadIdx.x] = src[(size_t)(l0 + threadIdx.y) * HDIM + j0 + threadIdx.x];
    __syncthreads();
    float* dst = ws + WT_OFF + (size_t)slot * HDIM * HDIM;
    dst[(size_t)(j0 + threadIdx.y) * HDIM + (l0 + threadIdx.x)] = t[threadIdx.x][threadIdx.y];
}

// WX0T[j][l'] = Wx0[l'][j]  (256x1024 -> 1024x256)
__global__ void k_pack_wx0(const float* __restrict__ Wx0, float* __restrict__ ws) {
    __shared__ float t[32][33];
    int j0 = blockIdx.x * 32, l0 = blockIdx.y * 32;   // grid (32, 8)
    t[threadIdx.y][threadIdx.x] = Wx0[(size_t)(l0 + threadIdx.y) * HDIM + j0 + threadIdx.x];
    __syncthreads();
    ws[WX0T_OFF + (size_t)(j0 + threadIdx.y) * IDIM + (l0 + threadIdx.x)] = t[threadIdx.x][threadIdx.y];
}

// zero open-loop state buffers + barrier flags/gen (runs every launch)
__global__ void k_init(float* __restrict__ ws) {
    int t = blockIdx.x * blockDim.x + threadIdx.x;   // grid(16) x 512
    if (t < 8192) ws[OBUF_OFF + t] = 0.f;
    if (t < 4096) g_flags[t] = 0u;
    if (t == 0)   g_gen = 0u;
}

// ---------------- scan kernel ----------------

__device__ __forceinline__ float wsum(float v) {
#pragma unroll
    for (int off = 32; off > 0; off >>= 1) v += __shfl_xor(v, off, 64);
    return v;
}

// Grid barrier #g (g = 1,2,3,... monotone). No RMW:
//  - every WG release-stores g to its own flag line
//  - WG0 wave0 polls all 256 flags lane-parallel, publishes g_gen
//  - others spin on g_gen, then acquire-fence
__device__ __forceinline__ void gbar(unsigned g) {
    __syncthreads();
    if (blockIdx.x == 0) {
        if (threadIdx.x < 64) {
            if (threadIdx.x == 0)
                __hip_atomic_store(&g_flags[0], g, __ATOMIC_RELEASE, __HIP_MEMORY_SCOPE_AGENT);
            const unsigned* fp = g_flags + threadIdx.x * 16;  // lane L -> WGs L, L+64, L+128, L+192
            for (;;) {
                bool ok = (__hip_atomic_load(fp,          __ATOMIC_RELAXED, __HIP_MEMORY_SCOPE_AGENT) >= g)
                       && (__hip_atomic_load(fp + 1024,   __ATOMIC_RELAXED, __HIP_MEMORY_SCOPE_AGENT) >= g)
                       && (__hip_atomic_load(fp + 2048,   __ATOMIC_RELAXED, __HIP_MEMORY_SCOPE_AGENT) >= g)
                       && (__hip_atomic_load(fp + 3072,   __ATOMIC_RELAXED, __HIP_MEMORY_SCOPE_AGENT) >= g);
                if (__all(ok)) break;
            }
            if (threadIdx.x == 0) {
                __threadfence();  // acquire for producers' data; also orders gen publish
                __hip_atomic_store(&g_gen, g, __ATOMIC_RELAXED, __HIP_MEMORY_SCOPE_AGENT);
            }
        }
        __syncthreads();
    } else {
        if (threadIdx.x == 0) {
            __hip_atomic_store(&g_flags[blockIdx.x * 16], g, __ATOMIC_RELEASE, __HIP_MEMORY_SCOPE_AGENT);
            while (__hip_atomic_load(&g_gen, __ATOMIC_RELAXED, __HIP_MEMORY_SCOPE_AGENT) < g)
                __builtin_amdgcn_s_sleep(1);
            __threadfence();  // acquire: invalidate stale L1/L2 before consuming others' h
        }
        __syncthreads();
    }
}

__global__ __launch_bounds__(TPB, 2) void k_scan(
    const float* __restrict__ xs, const float* __restrict__ b0,
    const float* __restrict__ brest, const float* __restrict__ outW,
    const float* __restrict__ outb, float* __restrict__ ws, float* __restrict__ out)
{
    const int lane  = threadIdx.x & 63;
    const int wv    = threadIdx.x >> 6;
    const int g     = blockIdx.x * WPB + wv;    // 0..2047
    const int layer = g >> 9;                   // 512 waves per layer
    const int jp    = g & 511;
    const int j0    = jp * 2;                   // this wave owns columns j0, j0+1

    const float* WX0T = ws + WX0T_OFF;
    const float* bfv  = ws + BF_OFF;
    float* obuf = ws + OBUF_OFF;
    float* cbuf = ws + CBUF_OFF;
    unsigned barc = 0;

    // -- preload weight columns into VGPRs (coalesced; one-time) --
    float A0[16], A1[16], B0[16], B1[16];
    {
        const float* a = ws + ((size_t)(2 * layer) * HDIM + j0) * HDIM;
        const float* b = ws + ((size_t)(2 * layer + 1) * HDIM + j0) * HDIM;
#pragma unroll
        for (int k = 0; k < 16; ++k) {
            A0[k] = a[lane + 64 * k];  A1[k] = a[HDIM + lane + 64 * k];
            B0[k] = b[lane + 64 * k];  B1[k] = b[HDIM + lane + 64 * k];
        }
    }
    float wx0a[4] = {0,0,0,0}, wx0b[4] = {0,0,0,0};
    if (layer == 0) {
        const float* p = WX0T + (size_t)j0 * IDIM;
#pragma unroll
        for (int k = 0; k < 4; ++k) { wx0a[k] = p[lane + 64 * k]; wx0b[k] = p[IDIM + lane + 64 * k]; }
    }
    const bool outwave = (layer == 3) && (jp < IDIM);
    float ow[16]; float ob = 0.f;
    if (outwave) {
        const float* p = outW + (size_t)jp * HDIM;
#pragma unroll
        for (int k = 0; k < 16; ++k) ow[k] = p[lane + 64 * k];
        ob = outb[jp];
    }
    float bias0, bias1, bf0 = 0.f, bf1 = 0.f;
    if (layer == 0) { bias0 = b0[j0]; bias1 = b0[j0 + 1]; bf0 = bfv[j0]; bf1 = bfv[j0 + 1]; }
    else            { bias0 = brest[(layer - 1) * HDIM + j0]; bias1 = brest[(layer - 1) * HDIM + j0 + 1]; }

    float hl0 = 0.f, hl1 = 0.f;   // this wave's h at t = SEQ-1 (closed-loop init)

    // ---- PHASE 1: open loop, wavefront over layers (step s: layer i does t = s-i) ----
    for (int s = 0; s <= SEQ + 3; ++s) {
        const float* R  = obuf + (s & 1) * 4096;         // state written at step s-1
        float*       Wb = obuf + ((s + 1) & 1) * 4096;   // state for step s+1
        const int t = s - layer;
        if (t >= 0 && t < SEQ) {
            float acc0 = 0.f, acc1 = 0.f;
            if (layer == 0) {
                const float* xr = xs + (size_t)t * IDIM;
#pragma unroll
                for (int k = 0; k < 4; ++k) {
                    float x = xr[lane + 64 * k];
                    acc0 += x * wx0a[k]; acc1 += x * wx0b[k];
                }
            } else {
                const float* hin = R + (layer - 1) * HDIM;   // h_{layer-1}^t
#pragma unroll
                for (int k = 0; k < 16; ++k) {
                    float x = hin[lane + 64 * k];
                    acc0 += x * A0[k]; acc1 += x * A1[k];
                }
            }
            const float* hpr = R + layer * HDIM;             // h_layer^{t-1}
#pragma unroll
            for (int k = 0; k < 16; ++k) {
                float x = hpr[lane + 64 * k];
                acc0 += x * B0[k]; acc1 += x * B1[k];
            }
            acc0 = wsum(acc0); acc1 = wsum(acc1);
            float r0 = tanhf(acc0 + bias0);
            float r1 = tanhf(acc1 + bias1);
            if (lane == 0) {
                Wb[layer * HDIM + j0]     = r0;
                Wb[layer * HDIM + j0 + 1] = r1;
            }
            if (t == SEQ - 1) { hl0 = r0; hl1 = r1; }
        }
        // open-loop output rows: out[t'] = out_W @ h3^{t'} + out_b, t' = s-4
        if (outwave && s >= 4) {
            const float* h3 = R + 3 * HDIM;
            float acc = 0.f;
#pragma unroll
            for (int k = 0; k < 16; ++k) acc += h3[lane + 64 * k] * ow[k];
            acc = wsum(acc);
            if (lane == 0) out[(size_t)(s - 4) * IDIM + jp] = acc + ob;
        }
        gbar(++barc);
    }

    // init closed-loop "prev" state (parity buffer 1) from registers
    if (lane == 0) {
        cbuf[4096 + layer * HDIM + j0]     = hl0;
        cbuf[4096 + layer * HDIM + j0 + 1] = hl1;
    }
    gbar(++barc);

    // ---- PHASE 2: closed loop. Stage 0 fused: h0 = tanh(h3_prev@W_fused + h0_prev@Wh0 + b_fused)
    for (int t = 0; t < NSTEPS; ++t) {
        float*       cur  = cbuf + (t & 1) * 4096;
        const float* prev = cbuf + ((t + 1) & 1) * 4096;
        // stage 0 (layer-0 waves); idle layer-3 out-waves emit output row t-1
        if (layer == 0) {
            float acc0 = 0.f, acc1 = 0.f;
            const float* h3 = prev + 3 * HDIM;
            const float* h0 = prev;
#pragma unroll
            for (int k = 0; k < 16; ++k) {
                float x = h3[lane + 64 * k]; acc0 += x * A0[k]; acc1 += x * A1[k];
                float y = h0[lane + 64 * k]; acc0 += y * B0[k]; acc1 += y * B1[k];
            }
            acc0 = wsum(acc0); acc1 = wsum(acc1);
            float r0 = tanhf(acc0 + bf0);
            float r1 = tanhf(acc1 + bf1);
            if (lane == 0) { cur[j0] = r0; cur[j0 + 1] = r1; }
        } else if (outwave && t > 0) {
            const float* h3 = prev + 3 * HDIM;   // h3^{t-1}
            float acc = 0.f;
#pragma unroll
            for (int k = 0; k < 16; ++k) acc += h3[lane + 64 * k] * ow[k];
            acc = wsum(acc);
            if (lane == 0) out[(size_t)(SEQ + t - 1) * IDIM + jp] = acc + ob;
        }
        gbar(++barc);
        // stages 1..3
        for (int i = 1; i < 4; ++i) {
            if (layer == i) {
                const float* hin = cur + (i - 1) * HDIM;   // h_{i-1}^t
                const float* hpr = prev + i * HDIM;        // h_i^{t-1}
                float acc0 = 0.f, acc1 = 0.f;
#pragma unroll
                for (int k = 0; k < 16; ++k) {
                    float x = hin[lane + 64 * k]; acc0 += x * A0[k]; acc1 += x * A1[k];
                    float y = hpr[lane + 64 * k]; acc0 += y * B0[k]; acc1 += y * B1[k];
                }
                acc0 = wsum(acc0); acc1 = wsum(acc1);
                float r0 = tanhf(acc0 + bias0);
                float r1 = tanhf(acc1 + bias1);
                if (lane == 0) { cur[i * HDIM + j0] = r0; cur[i * HDIM + j0 + 1] = r1; }
            }
            gbar(++barc);
        }
    }
    // epilogue: final output row from h3^{NSTEPS-1}
    if (outwave) {
        const float* h3 = cbuf + ((NSTEPS - 1) & 1) * 4096 + 3 * HDIM;
        float acc = 0.f;
#pragma unroll
        for (int k = 0; k < 16; ++k) acc += h3[lane + 64 * k] * ow[k];
        acc = wsum(acc);
        if (lane == 0) out[(size_t)(SEQ + NSTEPS - 1) * IDIM + jp] = acc + ob;
    }
}

// ---------------- launcher ----------------

extern "C" void kernel_launch(void* const* d_in, const int* in_sizes, int n_in,
                              void* d_out, int out_size, void* d_ws, size_t ws_size,
                              hipStream_t stream) {
    (void)in_sizes; (void)n_in; (void)out_size; (void)ws_size;
    const float* xs   = (const float*)d_in[0];
    const float* Wx0  = (const float*)d_in[1];
    const float* Wh0  = (const float*)d_in[2];
    const float* b0   = (const float*)d_in[3];
    const float* Wxr  = (const float*)d_in[4];
    const float* Whr  = (const float*)d_in[5];
    const float* brst = (const float*)d_in[6];
    const float* outW = (const float*)d_in[7];
    const float* outb = (const float*)d_in[8];
    float* ws  = (float*)d_ws;
    float* out = (float*)d_out;

    k_fuse_w<<<dim3(4, HDIM), dim3(256), 0, stream>>>(outW, Wx0, ws);
    k_fuse_b<<<dim3(4), dim3(256), 0, stream>>>(b0, outb, Wx0, ws);
    k_pack<<<dim3(32, 32, 7), dim3(32, 32), 0, stream>>>(Wh0, Wxr, Whr, ws);
    k_pack_wx0<<<dim3(32, 8), dim3(32, 32), 0, stream>>>(Wx0, ws);
    k_init<<<dim3(16), dim3(512), 0, stream>>>(ws);

    void* args[] = { (void*)&xs, (void*)&b0, (void*)&brst, (void*)&outW,
                     (void*)&outb, (void*)&ws, (void*)&out };
    hipError_t e = hipLaunchCooperativeKernel((void*)k_scan, dim3(NWG), dim3(TPB),
                                              args, 0, stream);
    if (e != hipSuccess) {
        // fallback: plain launch (2048 waves on 256 CUs = 4x co-residency headroom)
        k_scan<<<dim3(NWG), dim3(TPB), 0, stream>>>(xs, b0, brst, outW, outb, ws, out);
    }
}

// Round 3
// 54387.897 us; speedup vs baseline: 5.0578x; 3.3733x over previous
//
#include <hip/hip_runtime.h>
#include <math.h>

#define SEQ    8192
#define NSTEPS 2048
#define IDIM   256
#define HDIM   1024

#define NWG    256      // workgroups in cooperative grid
#define TPB    512      // threads per block = 8 waves
#define WPB    8        // waves per block

typedef unsigned long long u64;

// ---- workspace layout (in floats) ----
// WT: packed transposed weights, 8 slots of [1024][1024]: slot(2i)=A_i cols, slot(2i+1)=B_i cols
//     A_0 = W_fused = out_W^T @ Wx0 ; A_i = Wx_rest[i-1] (i>=1) ; B_0 = Wh0 ; B_i = Wh_rest[i-1]
//     WT[slot][j][l] = M[l][j]  (column j contiguous over row index l -> coalesced lane loads)
#define WT_OFF   0ull
#define WT_SZ    (8ull*HDIM*HDIM)
#define WX0T_OFF (WT_OFF + WT_SZ)            // WX0T[j][l'] = Wx0[l'][j], 1024x256
#define WX0T_SZ  ((unsigned long long)HDIM*IDIM)
#define BF_OFF   (WX0T_OFF + WX0T_SZ)        // b_fused[1024]
#define OBUF_OFF (BF_OFF + HDIM)             // open-loop state, double-buffered [2][4][1024]
#define CBUF_OFF (OBUF_OFF + 8192ull)        // closed-loop state, double-buffered [2][4][1024]

// per-WG arrival flags, 128B stride (one cache line each). Zeroed by k_init every launch.
__device__ unsigned g_flags[NWG * 32];

// ---------------- setup kernels ----------------

__global__ void k_fuse_w(const float* __restrict__ outW, const float* __restrict__ Wx0,
                         float* __restrict__ ws) {
    int l = blockIdx.x * 256 + threadIdx.x;   // grid (4, 1024)
    int j = blockIdx.y;
    float acc = 0.f;
    for (int k = 0; k < IDIM; ++k)
        acc += outW[(size_t)k * HDIM + l] * Wx0[(size_t)k * HDIM + j];
    ws[WT_OFF + (size_t)j * HDIM + l] = acc;
}

__global__ void k_fuse_b(const float* __restrict__ b0, const float* __restrict__ outb,
                         const float* __restrict__ Wx0, float* __restrict__ ws) {
    int j = blockIdx.x * 256 + threadIdx.x;   // grid (4)
    float acc = b0[j];
    for (int k = 0; k < IDIM; ++k)
        acc += outb[k] * Wx0[(size_t)k * HDIM + j];
    ws[BF_OFF + j] = acc;
}

__global__ void k_pack(const float* __restrict__ Wh0, const float* __restrict__ Wxr,
                       const float* __restrict__ Whr, float* __restrict__ ws) {
    __shared__ float t[32][33];
    int z = blockIdx.z;
    const float* src; int slot;
    if (z == 0)      { src = Wh0;                                  slot = 1; }
    else if (z <= 3) { src = Wxr + (size_t)(z - 1) * HDIM * HDIM;  slot = 2 * z; }
    else             { src = Whr + (size_t)(z - 4) * HDIM * HDIM;  slot = 2 * (z - 4) + 3; }
    int j0 = blockIdx.x * 32, l0 = blockIdx.y * 32;
    t[threadIdx.y][threadIdx.x] = src[(size_t)(l0 + threadIdx.y) * HDIM + j0 + threadIdx.x];
    __syncthreads();
    float* dst = ws + WT_OFF + (size_t)slot * HDIM * HDIM;
    dst[(size_t)(j0 + threadIdx.y) * HDIM + (l0 + threadIdx.x)] = t[threadIdx.x][threadIdx.y];
}

__global__ void k_pack_wx0(const float* __restrict__ Wx0, float* __restrict__ ws) {
    __shared__ float t[32][33];
    int j0 = blockIdx.x * 32, l0 = blockIdx.y * 32;   // grid (32, 8)
    t[threadIdx.y][threadIdx.x] = Wx0[(size_t)(l0 + threadIdx.y) * HDIM + j0 + threadIdx.x];
    __syncthreads();
    ws[WX0T_OFF + (size_t)(j0 + threadIdx.y) * IDIM + (l0 + threadIdx.x)] = t[threadIdx.x][threadIdx.y];
}

// zero open-loop state buffers + barrier flags (runs every launch)
__global__ void k_init(float* __restrict__ ws) {
    int t = blockIdx.x * blockDim.x + threadIdx.x;   // grid(16) x 512 = 8192
    ws[OBUF_OFF + t] = 0.f;
    g_flags[t] = 0u;
}

// ---------------- scan kernel ----------------

__device__ __forceinline__ float wsum(float v) {
#pragma unroll
    for (int off = 32; off > 0; off >>= 1) v += __shfl_xor(v, off, 64);
    return v;
}

__device__ __forceinline__ u64 ald(const u64* p) {
    return __hip_atomic_load(p, __ATOMIC_RELAXED, __HIP_MEMORY_SCOPE_AGENT);
}
__device__ __forceinline__ void ast(u64* p, u64 v) {
    __hip_atomic_store(p, v, __ATOMIC_RELAXED, __HIP_MEMORY_SCOPE_AGENT);
}
__device__ __forceinline__ float2 uf(u64 v) { union { u64 u; float2 f; } c; c.u = v; return c.f; }
__device__ __forceinline__ u64 fu(float a, float b) {
    union { u64 u; float2 f; } c; c.f = make_float2(a, b); return c.u;
}

// Fence-free all-to-all grid barrier. Data exchange is via relaxed agent (sc1,
// LLC-through) atomics, and __syncthreads drains vmcnt(0) per wave, so every
// WG's data stores are committed at the coherent LLC before its flag store.
// No master hop: each WG's wave 0 polls all 256 flags lane-parallel.
__device__ __forceinline__ void gbar(unsigned g) {
    __syncthreads();
    if (threadIdx.x == 0)
        __hip_atomic_store(&g_flags[blockIdx.x * 32], g, __ATOMIC_RELAXED, __HIP_MEMORY_SCOPE_AGENT);
    if (threadIdx.x < 64) {
        const unsigned* fp = g_flags + threadIdx.x * 32;  // lane L -> WGs L, L+64, L+128, L+192
        for (;;) {
            unsigned a0 = __hip_atomic_load(fp,            __ATOMIC_RELAXED, __HIP_MEMORY_SCOPE_AGENT);
            unsigned a1 = __hip_atomic_load(fp + 64 * 32,  __ATOMIC_RELAXED, __HIP_MEMORY_SCOPE_AGENT);
            unsigned a2 = __hip_atomic_load(fp + 128 * 32, __ATOMIC_RELAXED, __HIP_MEMORY_SCOPE_AGENT);
            unsigned a3 = __hip_atomic_load(fp + 192 * 32, __ATOMIC_RELAXED, __HIP_MEMORY_SCOPE_AGENT);
            if (__all((a0 >= g) && (a1 >= g) && (a2 >= g) && (a3 >= g))) break;
            __builtin_amdgcn_s_sleep(1);
        }
    }
    __syncthreads();
}

__global__ __launch_bounds__(TPB, 2) void k_scan(
    const float* __restrict__ xs, const float* __restrict__ b0,
    const float* __restrict__ brest, const float* __restrict__ outW,
    const float* __restrict__ outb, float* __restrict__ ws, float* __restrict__ out)
{
    const int lane  = threadIdx.x & 63;
    const int wv    = threadIdx.x >> 6;
    const int g     = blockIdx.x * WPB + wv;    // 0..2047
    const int layer = g >> 9;                   // 512 waves per layer
    const int jp    = g & 511;
    const int j0    = jp * 2;                   // this wave owns columns j0, j0+1

    const float* bfv  = ws + BF_OFF;
    float* obuf = ws + OBUF_OFF;
    float* cbuf = ws + CBUF_OFF;
    unsigned barc = 0;

    // -- preload weight column pairs into VGPRs (float2, matches u64 h-loads) --
    // element pair for (lane, k): h[2*(lane+64k)], h[2*(lane+64k)+1]
    float2 A0p[8], A1p[8], B0p[8], B1p[8];
    {
        const float2* a2 = (const float2*)(ws + ((size_t)(2 * layer) * HDIM + j0) * HDIM);
        const float2* b2 = (const float2*)(ws + ((size_t)(2 * layer + 1) * HDIM + j0) * HDIM);
#pragma unroll
        for (int k = 0; k < 8; ++k) {
            A0p[k] = a2[lane + 64 * k];  A1p[k] = a2[512 + lane + 64 * k];
            B0p[k] = b2[lane + 64 * k];  B1p[k] = b2[512 + lane + 64 * k];
        }
    }
    float2 wxap[2], wxbp[2];
    wxap[0] = wxap[1] = wxbp[0] = wxbp[1] = make_float2(0.f, 0.f);
    if (layer == 0) {
        const float2* p2 = (const float2*)(ws + WX0T_OFF + (size_t)j0 * IDIM);
#pragma unroll
        for (int k = 0; k < 2; ++k) { wxap[k] = p2[lane + 64 * k]; wxbp[k] = p2[128 + lane + 64 * k]; }
    }
    const bool outwave = (layer == 3) && (jp < IDIM);
    float2 owp[8]; float ob = 0.f;
    if (outwave) {
        const float2* p2 = (const float2*)(outW + (size_t)jp * HDIM);
#pragma unroll
        for (int k = 0; k < 8; ++k) owp[k] = p2[lane + 64 * k];
        ob = outb[jp];
    }
    float bias0, bias1, bf0 = 0.f, bf1 = 0.f;
    if (layer == 0) { bias0 = b0[j0]; bias1 = b0[j0 + 1]; bf0 = bfv[j0]; bf1 = bfv[j0 + 1]; }
    else            { bias0 = brest[(layer - 1) * HDIM + j0]; bias1 = brest[(layer - 1) * HDIM + j0 + 1]; }

    float hl0 = 0.f, hl1 = 0.f;   // this wave's h at t = SEQ-1 (closed-loop init)

    // ---- PHASE 1: open loop, wavefront over layers (step s: layer i does t = s-i) ----
    for (int s = 0; s <= SEQ + 3; ++s) {
        float* Rf = obuf + (s & 1) * 4096;         // state written at step s-1
        float* Wb = obuf + ((s + 1) & 1) * 4096;   // state for step s+1
        const int t = s - layer;
        if (t >= 0 && t < SEQ) {
            float2 Y[8];
            const u64* hp = (const u64*)(Rf + layer * HDIM);
#pragma unroll
            for (int k = 0; k < 8; ++k) Y[k] = uf(ald(hp + lane + 64 * k));
            float acc0 = 0.f, acc1 = 0.f;
            if (layer == 0) {
                const float2* xr = (const float2*)(xs + (size_t)t * IDIM);
                float2 x0 = xr[lane], x1 = xr[lane + 64];
                acc0 = x0.x * wxap[0].x + x0.y * wxap[0].y + x1.x * wxap[1].x + x1.y * wxap[1].y;
                acc1 = x0.x * wxbp[0].x + x0.y * wxbp[0].y + x1.x * wxbp[1].x + x1.y * wxbp[1].y;
            } else {
                float2 X[8];
                const u64* hi = (const u64*)(Rf + (layer - 1) * HDIM);
#pragma unroll
                for (int k = 0; k < 8; ++k) X[k] = uf(ald(hi + lane + 64 * k));
#pragma unroll
                for (int k = 0; k < 8; ++k) {
                    acc0 += X[k].x * A0p[k].x + X[k].y * A0p[k].y;
                    acc1 += X[k].x * A1p[k].x + X[k].y * A1p[k].y;
                }
            }
#pragma unroll
            for (int k = 0; k < 8; ++k) {
                acc0 += Y[k].x * B0p[k].x + Y[k].y * B0p[k].y;
                acc1 += Y[k].x * B1p[k].x + Y[k].y * B1p[k].y;
            }
            acc0 = wsum(acc0); acc1 = wsum(acc1);
            float r0 = tanhf(acc0 + bias0);
            float r1 = tanhf(acc1 + bias1);
            if (lane == 0) ast((u64*)(Wb + layer * HDIM + j0), fu(r0, r1));
            if (t == SEQ - 1) { hl0 = r0; hl1 = r1; }
        }
        // open-loop output rows: out[t'] = out_W @ h3^{t'} + out_b, t' = s-4
        if (outwave && s >= 4) {
            float2 Z[8];
            const u64* h3 = (const u64*)(Rf + 3 * HDIM);
#pragma unroll
            for (int k = 0; k < 8; ++k) Z[k] = uf(ald(h3 + lane + 64 * k));
            float acc = 0.f;
#pragma unroll
            for (int k = 0; k < 8; ++k) acc += Z[k].x * owp[k].x + Z[k].y * owp[k].y;
            acc = wsum(acc);
            if (lane == 0) out[(size_t)(s - 4) * IDIM + jp] = acc + ob;
        }
        gbar(++barc);
    }

    // init closed-loop "prev" state (parity buffer 1) from registers
    if (lane == 0) ast((u64*)(cbuf + 4096 + layer * HDIM + j0), fu(hl0, hl1));
    gbar(++barc);

    // ---- PHASE 2: closed loop. Stage 0 fused: h0 = tanh(h3_prev@W_fused + h0_prev@Wh0 + b_fused)
    for (int t = 0; t < NSTEPS; ++t) {
        float*       cur  = cbuf + (t & 1) * 4096;
        const float* prev = cbuf + ((t + 1) & 1) * 4096;

        // preload: own prev state (final since last barrier of step t-1)
        float2 Y[8];
        {
            const u64* hp = (const u64*)(prev + layer * HDIM);
#pragma unroll
            for (int k = 0; k < 8; ++k) Y[k] = uf(ald(hp + lane + 64 * k));
        }
        float2 Z[8];   // h3_prev, needed by layer 0 (for layer 3 it IS Y)
        if (layer == 0) {
            const u64* h3 = (const u64*)(prev + 3 * HDIM);
#pragma unroll
            for (int k = 0; k < 8; ++k) Z[k] = uf(ald(h3 + lane + 64 * k));
        }

        // stage 0: layer-0 update (fully preloaded); idle out-waves emit out row t-1
        if (layer == 0) {
            float acc0 = 0.f, acc1 = 0.f;
#pragma unroll
            for (int k = 0; k < 8; ++k) {
                acc0 += Z[k].x * A0p[k].x + Z[k].y * A0p[k].y + Y[k].x * B0p[k].x + Y[k].y * B0p[k].y;
                acc1 += Z[k].x * A1p[k].x + Z[k].y * A1p[k].y + Y[k].x * B1p[k].x + Y[k].y * B1p[k].y;
            }
            acc0 = wsum(acc0); acc1 = wsum(acc1);
            float r0 = tanhf(acc0 + bf0);
            float r1 = tanhf(acc1 + bf1);
            if (lane == 0) ast((u64*)(cur + j0), fu(r0, r1));
        } else if (outwave && t > 0) {
            float acc = 0.f;   // Y = h3^{t-1}
#pragma unroll
            for (int k = 0; k < 8; ++k) acc += Y[k].x * owp[k].x + Y[k].y * owp[k].y;
            acc = wsum(acc);
            if (lane == 0) out[(size_t)(SEQ + t - 1) * IDIM + jp] = acc + ob;
        }
        gbar(++barc);

        // stages 1..3: layer i loads fresh h_{i-1}^t, combines with preloaded Y
#pragma unroll 1
        for (int i = 1; i < 4; ++i) {
            if (layer == i) {
                float2 X[8];
                const u64* hi = (const u64*)(cur + (i - 1) * HDIM);
#pragma unroll
                for (int k = 0; k < 8; ++k) X[k] = uf(ald(hi + lane + 64 * k));
                float acc0 = 0.f, acc1 = 0.f;
#pragma unroll
                for (int k = 0; k < 8; ++k) {
                    acc0 += X[k].x * A0p[k].x + X[k].y * A0p[k].y + Y[k].x * B0p[k].x + Y[k].y * B0p[k].y;
                    acc1 += X[k].x * A1p[k].x + X[k].y * A1p[k].y + Y[k].x * B1p[k].x + Y[k].y * B1p[k].y;
                }
                acc0 = wsum(acc0); acc1 = wsum(acc1);
                float r0 = tanhf(acc0 + bias0);
                float r1 = tanhf(acc1 + bias1);
                if (lane == 0) ast((u64*)(cur + i * HDIM + j0), fu(r0, r1));
            }
            gbar(++barc);
        }
    }
    // epilogue: final output row from h3^{NSTEPS-1}
    if (outwave) {
        const u64* h3 = (const u64*)(cbuf + ((NSTEPS - 1) & 1) * 4096 + 3 * HDIM);
        float acc = 0.f;
#pragma unroll
        for (int k = 0; k < 8; ++k) { float2 z = uf(ald(h3 + lane + 64 * k)); acc += z.x * owp[k].x + z.y * owp[k].y; }
        acc = wsum(acc);
        if (lane == 0) out[(size_t)(SEQ + NSTEPS - 1) * IDIM + jp] = acc + ob;
    }
}

// ---------------- launcher ----------------

extern "C" void kernel_launch(void* const* d_in, const int* in_sizes, int n_in,
                              void* d_out, int out_size, void* d_ws, size_t ws_size,
                              hipStream_t stream) {
    (void)in_sizes; (void)n_in; (void)out_size; (void)ws_size;
    const float* xs   = (const float*)d_in[0];
    const float* Wx0  = (const float*)d_in[1];
    const float* Wh0  = (const float*)d_in[2];
    const float* b0   = (const float*)d_in[3];
    const float* Wxr  = (const float*)d_in[4];
    const float* Whr  = (const float*)d_in[5];
    const float* brst = (const float*)d_in[6];
    const float* outW = (const float*)d_in[7];
    const float* outb = (const float*)d_in[8];
    float* ws  = (float*)d_ws;
    float* out = (float*)d_out;

    k_fuse_w<<<dim3(4, HDIM), dim3(256), 0, stream>>>(outW, Wx0, ws);
    k_fuse_b<<<dim3(4), dim3(256), 0, stream>>>(b0, outb, Wx0, ws);
    k_pack<<<dim3(32, 32, 7), dim3(32, 32), 0, stream>>>(Wh0, Wxr, Whr, ws);
    k_pack_wx0<<<dim3(32, 8), dim3(32, 32), 0, stream>>>(Wx0, ws);
    k_init<<<dim3(16), dim3(512), 0, stream>>>(ws);

    void* args[] = { (void*)&xs, (void*)&b0, (void*)&brst, (void*)&outW,
                     (void*)&outb, (void*)&ws, (void*)&out };
    hipError_t e = hipLaunchCooperativeKernel((void*)k_scan, dim3(NWG), dim3(TPB),
                                              args, 0, stream);
    if (e != hipSuccess) {
        // fallback: plain launch (2048 waves on 256 CUs, 1 block/CU)
        k_scan<<<dim3(NWG), dim3(TPB), 0, stream>>>(xs, b0, brst, outW, outb, ws, out);
    }
}

// Round 4
// 51432.861 us; speedup vs baseline: 5.3484x; 1.0575x over previous
//
#include <hip/hip_runtime.h>
#include <math.h>

#define SEQ    8192
#define NSTEPS 2048
#define NTOT   (SEQ + NSTEPS)   // 10240 steps per layer, unified open-loop + AR stream
#define IDIM   256
#define HDIM   1024

#define NWG    256      // 64 WGs per layer
#define TPB    256      // 4 waves per WG
#define WPB    4
#define RD     8        // ring depth (power of 2)

typedef unsigned long long u64;

// ---- workspace layout (floats) ----
// WT: 8 slots [1024][1024] transposed weights: slot(2i)=A_i cols, slot(2i+1)=B_i cols
//     A_0 = W_fused = out_W^T @ Wx0 (phase-2 only); A_i = Wx_rest[i-1]; B_i = Wh matrices
//     WT[slot][j][l] = M[l][j]
// BF:  b_fused[1024]
// RING: 4 layers x RD slots x 1024 u64, each u64 = (step_tag<<32)|f32bits
// PROG: 256 u32, per-WG progress (step whose inputs are fully captured)
#define WT_FLOATS   (8ull*HDIM*HDIM)
#define BF_FLOAT    WT_FLOATS
#define RING_FLOAT  (WT_FLOATS + HDIM)
#define RING_U64S   (4ull*RD*HDIM)          // 32768
#define PROG_FLOAT  (RING_FLOAT + 2ull*RING_U64S)

// ---------------- setup kernels ----------------

// WT slot 0 (transposed W_fused): WT0[j][l] = sum_k out_W[k][l] * Wx0[k][j]
__global__ void k_fuse_w(const float* __restrict__ outW, const float* __restrict__ Wx0,
                         float* __restrict__ ws) {
    int l = blockIdx.x * 256 + threadIdx.x;   // grid (4, 1024)
    int j = blockIdx.y;
    float acc = 0.f;
    for (int k = 0; k < IDIM; ++k)
        acc += outW[(size_t)k * HDIM + l] * Wx0[(size_t)k * HDIM + j];
    ws[(size_t)j * HDIM + l] = acc;
}

// b_fused[j] = b0[j] + sum_k out_b[k] * Wx0[k][j]
__global__ void k_fuse_b(const float* __restrict__ b0, const float* __restrict__ outb,
                         const float* __restrict__ Wx0, float* __restrict__ ws) {
    int j = blockIdx.x * 256 + threadIdx.x;   // grid (4)
    float acc = b0[j];
    for (int k = 0; k < IDIM; ++k)
        acc += outb[k] * Wx0[(size_t)k * HDIM + j];
    ws[BF_FLOAT + j] = acc;
}

// transpose-pack the seven 1024x1024 matrices into WT slots 1..7
__global__ void k_pack(const float* __restrict__ Wh0, const float* __restrict__ Wxr,
                       const float* __restrict__ Whr, float* __restrict__ ws) {
    __shared__ float t[32][33];
    int z = blockIdx.z;
    const float* src; int slot;
    if (z == 0)      { src = Wh0;                                  slot = 1; }
    else if (z <= 3) { src = Wxr + (size_t)(z - 1) * HDIM * HDIM;  slot = 2 * z; }
    else             { src = Whr + (size_t)(z - 4) * HDIM * HDIM;  slot = 2 * (z - 4) + 3; }
    int j0 = blockIdx.x * 32, l0 = blockIdx.y * 32;
    t[threadIdx.y][threadIdx.x] = src[(size_t)(l0 + threadIdx.y) * HDIM + j0 + threadIdx.x];
    __syncthreads();
    float* dst = ws + (size_t)slot * HDIM * HDIM;
    dst[(size_t)(j0 + threadIdx.y) * HDIM + (l0 + threadIdx.x)] = t[threadIdx.x][threadIdx.y];
}

// zero ring tags + progress (runs every launch; ws is poisoned 0xAA before each)
__global__ void k_init(float* __restrict__ ws) {
    int t = blockIdx.x * blockDim.x + threadIdx.x;   // grid(64) x 512 = 32768 == RING_U64S
    ((u64*)(ws + RING_FLOAT))[t] = 0ull;             // tag 0, value 0.0 == initial h state
    if (t < NWG) ((unsigned*)(ws + PROG_FLOAT))[t] = 0u;
}

// ---------------- scan kernel ----------------

__device__ __forceinline__ float wsum(float v) {
#pragma unroll
    for (int off = 32; off > 0; off >>= 1) v += __shfl_xor(v, off, 64);
    return v;
}

// Poll a 1024-elem tagged vector until every element carries tag `want`,
// then deposit the float payloads into LDS. The detecting iteration already
// holds the data — no separate fetch round trip, no flags, no fences
// (tag+value travel atomically in one u64).
__device__ __forceinline__ void capture_vec(const u64* slot, unsigned want,
                                            float* dst, int lane) {
    for (;;) {
        u64 v[16]; bool ok = true;
#pragma unroll
        for (int k = 0; k < 16; ++k) {
            v[k] = __hip_atomic_load(slot + lane + 64 * k, __ATOMIC_RELAXED, __HIP_MEMORY_SCOPE_AGENT);
            ok &= ((unsigned)(v[k] >> 32) == want);
        }
        if (__all(ok)) {
#pragma unroll
            for (int k = 0; k < 16; ++k) dst[lane + 64 * k] = __uint_as_float((unsigned)v[k]);
            return;
        }
    }
}

__global__ __launch_bounds__(TPB, 1) void k_scan(
    const float* __restrict__ xs, const float* __restrict__ Wx0,
    const float* __restrict__ b0, const float* __restrict__ brest,
    const float* __restrict__ outW, const float* __restrict__ outb,
    float* __restrict__ ws, float* __restrict__ out)
{
    const int lane  = threadIdx.x & 63;
    const int wv    = threadIdx.x >> 6;
    const int layer = blockIdx.x >> 6;      // 64 WGs per layer
    const int wgl   = blockIdx.x & 63;
    const int jw    = wgl * WPB + wv;       // wave index within layer, 0..255
    const int j0    = jw * 4;               // owns columns j0..j0+3

    __shared__ float ldsOwn[2][HDIM];       // own layer h^{n-1}, parity double-buffered
    __shared__ float ldsUp[2][HDIM];        // upstream input vector

    u64* ring = (u64*)(ws + RING_FLOAT);
    unsigned* prog = (unsigned*)(ws + PROG_FLOAT);
    const int cons = (layer + 1) & 3;       // downstream ring consumer layer

    // ---- one-time weight preload into VGPRs (coalesced from WT) ----
    float A[4][16], B[4][16];
#pragma unroll
    for (int c = 0; c < 4; ++c)
#pragma unroll
        for (int k = 0; k < 16; ++k) {
            A[c][k] = ws[((size_t)(2 * layer) * HDIM + (j0 + c)) * HDIM + lane + 64 * k];
            B[c][k] = ws[((size_t)(2 * layer + 1) * HDIM + (j0 + c)) * HDIM + lane + 64 * k];
        }
    float wx0[4][4];
    if (layer == 0) {
#pragma unroll
        for (int c = 0; c < 4; ++c)
#pragma unroll
            for (int k = 0; k < 4; ++k)
                wx0[c][k] = Wx0[(size_t)(lane + 64 * k) * HDIM + (j0 + c)];
    }
    float ow[16]; float obv = 0.f;
    if (layer == 3) {       // every layer-3 wave owns one output row (jw < 256)
#pragma unroll
        for (int k = 0; k < 16; ++k) ow[k] = outW[(size_t)jw * HDIM + lane + 64 * k];
        obv = outb[jw];
    }
    float bb[4], bfc[4];
#pragma unroll
    for (int c = 0; c < 4; ++c) {
        bb[c]  = (layer == 0) ? b0[j0 + c] : brest[(size_t)(layer - 1) * HDIM + j0 + c];
        bfc[c] = (layer == 0) ? ws[BF_FLOAT + j0 + c] : 0.f;
    }

    int minp = 0;   // cached min consumer progress (credit-based flow control)

    for (int n = 1; n <= NTOT; ++n) {
        const int par = n & 1;
        const bool xphase = (layer == 0) && (n <= SEQ);

        // prefetch xs row (independent of polls)
        float xv[4];
        if (xphase) {
            const float* xr = xs + (size_t)(n - 1) * IDIM;
#pragma unroll
            for (int k = 0; k < 4; ++k) xv[k] = xr[lane + 64 * k];
        }

        // capture inputs: wave0 -> own h^{n-1}; wave1 -> upstream vector
        if (wv == 0) {
            capture_vec(ring + ((size_t)layer * RD + ((n - 1) & (RD - 1))) * HDIM,
                        (unsigned)(n - 1), ldsOwn[par], lane);
        } else if (wv == 1 && !xphase) {
            const int ul = (layer == 0) ? 3 : layer - 1;
            const unsigned want = (layer == 0) ? (unsigned)(n - 1) : (unsigned)n;
            capture_vec(ring + ((size_t)ul * RD + (want & (RD - 1))) * HDIM,
                        want, ldsUp[par], lane);
        }
        __syncthreads();
        if (wv == 0 && lane == 0)
            __hip_atomic_store(&prog[blockIdx.x], (unsigned)n, __ATOMIC_RELAXED, __HIP_MEMORY_SCOPE_AGENT);

        // compute this wave's 4 columns
        float a0 = 0.f, a1 = 0.f, a2 = 0.f, a3 = 0.f;
        if (xphase) {
#pragma unroll
            for (int k = 0; k < 4; ++k) {
                float x = xv[k];
                a0 += x * wx0[0][k]; a1 += x * wx0[1][k]; a2 += x * wx0[2][k]; a3 += x * wx0[3][k];
            }
        } else {
#pragma unroll
            for (int k = 0; k < 16; ++k) {
                float x = ldsUp[par][lane + 64 * k];
                a0 += x * A[0][k]; a1 += x * A[1][k]; a2 += x * A[2][k]; a3 += x * A[3][k];
            }
        }
#pragma unroll
        for (int k = 0; k < 16; ++k) {
            float y = ldsOwn[par][lane + 64 * k];
            a0 += y * B[0][k]; a1 += y * B[1][k]; a2 += y * B[2][k]; a3 += y * B[3][k];
        }
        a0 = wsum(a0); a1 = wsum(a1); a2 = wsum(a2); a3 = wsum(a3);
        const bool fph = (layer == 0) && (n > SEQ);
        float r0 = tanhf(a0 + (fph ? bfc[0] : bb[0]));
        float r1 = tanhf(a1 + (fph ? bfc[1] : bb[1]));
        float r2 = tanhf(a2 + (fph ? bfc[2] : bb[2]));
        float r3 = tanhf(a3 + (fph ? bfc[3] : bb[3]));

        // backpressure: writing step n kills tag n-RD; consumer must have
        // captured step n-7 (conservative across both capture timings)
        if (minp < (int)n - 7) {
            for (;;) {
                unsigned pv = __hip_atomic_load(&prog[cons * 64 + lane],
                                                __ATOMIC_RELAXED, __HIP_MEMORY_SCOPE_AGENT);
#pragma unroll
                for (int off = 32; off > 0; off >>= 1) {
                    unsigned o = (unsigned)__shfl_xor((int)pv, off, 64);
                    pv = pv < o ? pv : o;
                }
                minp = (int)pv;
                if (minp >= (int)n - 7) break;
                __builtin_amdgcn_s_sleep(2);
            }
        }

        // publish tagged results (lanes 0..3 store one column each)
        {
            u64* dst = ring + ((size_t)layer * RD + (n & (RD - 1))) * HDIM + j0;
            if (lane < 4) {
                float v = (lane == 0) ? r0 : (lane == 1) ? r1 : (lane == 2) ? r2 : r3;
                __hip_atomic_store(dst + lane,
                                   ((u64)(unsigned)n << 32) | (u64)__float_as_uint(v),
                                   __ATOMIC_RELAXED, __HIP_MEMORY_SCOPE_AGENT);
            }
        }

        // out row n-2 = ow . h3^{n-1}: the operand is already in ldsOwn — free handoff
        if (layer == 3 && n >= 2) {
            float a = 0.f;
#pragma unroll
            for (int k = 0; k < 16; ++k) a += ldsOwn[par][lane + 64 * k] * ow[k];
            a = wsum(a);
            if (lane == 0) out[(size_t)(n - 2) * IDIM + jw] = a + obv;
        }
    }

    // epilogue: final output row from h3^{NTOT}
    if (layer == 3) {
        if (wv == 0)
            capture_vec(ring + ((size_t)3 * RD + (NTOT & (RD - 1))) * HDIM,
                        (unsigned)NTOT, ldsOwn[0], lane);
        __syncthreads();
        float a = 0.f;
#pragma unroll
        for (int k = 0; k < 16; ++k) a += ldsOwn[0][lane + 64 * k] * ow[k];
        a = wsum(a);
        if (lane == 0) out[(size_t)(NTOT - 1) * IDIM + jw] = a + obv;
    }
}

// ---------------- launcher ----------------

extern "C" void kernel_launch(void* const* d_in, const int* in_sizes, int n_in,
                              void* d_out, int out_size, void* d_ws, size_t ws_size,
                              hipStream_t stream) {
    (void)in_sizes; (void)n_in; (void)out_size; (void)ws_size;
    const float* xs   = (const float*)d_in[0];
    const float* Wx0  = (const float*)d_in[1];
    const float* Wh0  = (const float*)d_in[2];
    const float* b0   = (const float*)d_in[3];
    const float* Wxr  = (const float*)d_in[4];
    const float* Whr  = (const float*)d_in[5];
    const float* brst = (const float*)d_in[6];
    const float* outW = (const float*)d_in[7];
    const float* outb = (const float*)d_in[8];
    float* ws  = (float*)d_ws;
    float* out = (float*)d_out;

    k_fuse_w<<<dim3(4, HDIM), dim3(256), 0, stream>>>(outW, Wx0, ws);
    k_fuse_b<<<dim3(4), dim3(256), 0, stream>>>(b0, outb, Wx0, ws);
    k_pack<<<dim3(32, 32, 7), dim3(32, 32), 0, stream>>>(Wh0, Wxr, Whr, ws);
    k_init<<<dim3(64), dim3(512), 0, stream>>>(ws);

    void* args[] = { (void*)&xs, (void*)&Wx0, (void*)&b0, (void*)&brst,
                     (void*)&outW, (void*)&outb, (void*)&ws, (void*)&out };
    hipError_t e = hipLaunchCooperativeKernel((void*)k_scan, dim3(NWG), dim3(TPB),
                                              args, 0, stream);
    if (e != hipSuccess) {
        // fallback: plain launch (256 WGs x 256 thr = 1 WG/CU, all co-resident)
        k_scan<<<dim3(NWG), dim3(TPB), 0, stream>>>(xs, Wx0, b0, brst, outW, outb, ws, out);
    }
}

// Round 5
// 50002.496 us; speedup vs baseline: 5.5014x; 1.0286x over previous
//
#include <hip/hip_runtime.h>
#include <math.h>

#define SEQ    8192
#define NSTEPS 2048
#define NTOT   (SEQ + NSTEPS)   // 10240 unified steps per layer (open-loop + AR)
#define IDIM   256
#define HDIM   1024

#define NWG    128      // 32 WGs per layer
#define TPB    512      // 8 waves per WG
#define WPB    8
#define RD     8        // ring depth (power of 2)

typedef unsigned long long u64;

// ---- workspace layout (floats) ----
// WT: 8 slots [1024][1024] transposed weights: slot(2i)=A_i cols, slot(2i+1)=B_i cols
//     A_0 = W_fused = out_W^T @ Wx0 (AR phase); A_i = Wx_rest[i-1]; B_i = Wh matrices
// BF:  b_fused[1024]
// RING: 4 layers x RD slots x 1024 u64; u64 = (step_tag<<32)|f32bits
// PROG: NWG u32, per-WG progress (step whose inputs are fully captured)
#define WT_FLOATS   (8ull*HDIM*HDIM)
#define BF_FLOAT    WT_FLOATS
#define RING_FLOAT  (WT_FLOATS + HDIM)
#define RING_U64S   (4ull*RD*HDIM)          // 32768
#define PROG_FLOAT  (RING_FLOAT + 2ull*RING_U64S)

// ---------------- setup kernels ----------------

__global__ void k_fuse_w(const float* __restrict__ outW, const float* __restrict__ Wx0,
                         float* __restrict__ ws) {
    int l = blockIdx.x * 256 + threadIdx.x;   // grid (4, 1024)
    int j = blockIdx.y;
    float acc = 0.f;
    for (int k = 0; k < IDIM; ++k)
        acc += outW[(size_t)k * HDIM + l] * Wx0[(size_t)k * HDIM + j];
    ws[(size_t)j * HDIM + l] = acc;
}

__global__ void k_fuse_b(const float* __restrict__ b0, const float* __restrict__ outb,
                         const float* __restrict__ Wx0, float* __restrict__ ws) {
    int j = blockIdx.x * 256 + threadIdx.x;   // grid (4)
    float acc = b0[j];
    for (int k = 0; k < IDIM; ++k)
        acc += outb[k] * Wx0[(size_t)k * HDIM + j];
    ws[BF_FLOAT + j] = acc;
}

__global__ void k_pack(const float* __restrict__ Wh0, const float* __restrict__ Wxr,
                       const float* __restrict__ Whr, float* __restrict__ ws) {
    __shared__ float t[32][33];
    int z = blockIdx.z;
    const float* src; int slot;
    if (z == 0)      { src = Wh0;                                  slot = 1; }
    else if (z <= 3) { src = Wxr + (size_t)(z - 1) * HDIM * HDIM;  slot = 2 * z; }
    else             { src = Whr + (size_t)(z - 4) * HDIM * HDIM;  slot = 2 * (z - 4) + 3; }
    int j0 = blockIdx.x * 32, l0 = blockIdx.y * 32;
    t[threadIdx.y][threadIdx.x] = src[(size_t)(l0 + threadIdx.y) * HDIM + j0 + threadIdx.x];
    __syncthreads();
    float* dst = ws + (size_t)slot * HDIM * HDIM;
    dst[(size_t)(j0 + threadIdx.y) * HDIM + (l0 + threadIdx.x)] = t[threadIdx.x][threadIdx.y];
}

// zero ring tags + progress (every launch; ws is re-poisoned before each)
__global__ void k_init(float* __restrict__ ws) {
    int t = blockIdx.x * blockDim.x + threadIdx.x;   // grid(64) x 512 = 32768 == RING_U64S
    ((u64*)(ws + RING_FLOAT))[t] = 0ull;             // tag 0, value 0.0 == initial h state
    if (t < NWG) ((unsigned*)(ws + PROG_FLOAT))[t] = 0u;
}

// ---------------- scan kernel ----------------

__device__ __forceinline__ float wsum(float v) {
#pragma unroll
    for (int off = 32; off > 0; off >>= 1) v += __shfl_xor(v, off, 64);
    return v;
}

__device__ __forceinline__ float ftanh(float x) {
    x = fminf(15.f, fmaxf(-15.f, x));
    float e = __builtin_amdgcn_exp2f(x * 2.8853900817779268f);   // e^{2x}
    return (e - 1.f) * __builtin_amdgcn_rcpf(e + 1.f);
}

// Masked incremental capture of 8 tagged elements (k = kbase..kbase+7) per lane.
// Only not-yet-tagged elements are reloaded (predicated, concurrent issue), so
// steady-state poll traffic ~= one read of the vector + straggler retries.
// Detecting iteration already holds the payload (tag+value atomic in one u64).
__device__ __forceinline__ void capture8(const u64* slot, unsigned want,
                                         float* dst, int lane, int kbase) {
    unsigned done = 0;
    for (;;) {
        u64 v[8];
#pragma unroll
        for (int k = 0; k < 8; ++k) {
            v[k] = 0;
            if (!(done & (1u << k)))
                v[k] = __hip_atomic_load(slot + lane + 64 * (kbase + k),
                                         __ATOMIC_RELAXED, __HIP_MEMORY_SCOPE_AGENT);
        }
#pragma unroll
        for (int k = 0; k < 8; ++k) {
            if (!(done & (1u << k)) && ((unsigned)(v[k] >> 32) == want)) {
                dst[lane + 64 * (kbase + k)] = __uint_as_float((unsigned)v[k]);
                done |= 1u << k;
            }
        }
        if (__all(done == 0xFFu)) return;
    }
}

__global__ __launch_bounds__(TPB, 1) void k_scan(
    const float* __restrict__ xs, const float* __restrict__ Wx0,
    const float* __restrict__ b0, const float* __restrict__ brest,
    const float* __restrict__ outW, const float* __restrict__ outb,
    float* __restrict__ ws, float* __restrict__ out)
{
    const int lane  = threadIdx.x & 63;
    const int wv    = threadIdx.x >> 6;
    const int layer = blockIdx.x >> 5;      // 32 WGs per layer
    const int wgl   = blockIdx.x & 31;
    const int jw    = wgl * WPB + wv;       // wave index within layer, 0..255
    const int j0    = jw * 4;               // owns columns j0..j0+3

    __shared__ float ldsOwn[2][HDIM];       // own layer h^{n-1}, parity double-buffered
    __shared__ float ldsUp[2][HDIM];        // upstream input vector

    u64* ring = (u64*)(ws + RING_FLOAT);
    unsigned* prog = (unsigned*)(ws + PROG_FLOAT);
    const int cons = (layer + 1) & 3;       // downstream ring consumer layer

    // ---- one-time weight preload into VGPRs ----
    float A[4][16], B[4][16];
#pragma unroll
    for (int c = 0; c < 4; ++c)
#pragma unroll
        for (int k = 0; k < 16; ++k) {
            A[c][k] = ws[((size_t)(2 * layer) * HDIM + (j0 + c)) * HDIM + lane + 64 * k];
            B[c][k] = ws[((size_t)(2 * layer + 1) * HDIM + (j0 + c)) * HDIM + lane + 64 * k];
        }
    float wx0[4][4];
    if (layer == 0) {
#pragma unroll
        for (int c = 0; c < 4; ++c)
#pragma unroll
            for (int k = 0; k < 4; ++k)
                wx0[c][k] = Wx0[(size_t)(lane + 64 * k) * HDIM + (j0 + c)];
    }
    float ow[16]; float obv = 0.f;
    if (layer == 3) {       // each layer-3 wave owns one output row (jw = 0..255)
#pragma unroll
        for (int k = 0; k < 16; ++k) ow[k] = outW[(size_t)jw * HDIM + lane + 64 * k];
        obv = outb[jw];
    }
    float bb[4], bfc[4];
#pragma unroll
    for (int c = 0; c < 4; ++c) {
        bb[c]  = (layer == 0) ? b0[j0 + c] : brest[(size_t)(layer - 1) * HDIM + j0 + c];
        bfc[c] = (layer == 0) ? ws[BF_FLOAT + j0 + c] : 0.f;
    }

    int minp = 0;   // cached min consumer progress (credit-based flow control)

    for (int n = 1; n <= NTOT; ++n) {
        const int par = n & 1;
        const bool xphase = (layer == 0) && (n <= SEQ);

        // backpressure (off the publish path): writing slot n kills tag n-RD;
        // downstream consumer must have captured step n-7. Own-layer skew is
        // self-limited (peers are >= step n-1 when we reach step n).
        if (minp < n - 7) {
            for (;;) {
                unsigned pv = __hip_atomic_load(&prog[cons * 32 + (lane & 31)],
                                                __ATOMIC_RELAXED, __HIP_MEMORY_SCOPE_AGENT);
#pragma unroll
                for (int off = 32; off > 0; off >>= 1) {
                    unsigned o = (unsigned)__shfl_xor((int)pv, off, 64);
                    pv = pv < o ? pv : o;
                }
                minp = (int)pv;
                if (minp >= n - 7) break;
                __builtin_amdgcn_s_sleep(2);
            }
        }

        // prefetch xs row (independent of polls)
        float xv[4];
        if (xphase) {
            const float* xr = xs + (size_t)(n - 1) * IDIM;
#pragma unroll
            for (int k = 0; k < 4; ++k) xv[k] = xr[lane + 64 * k];
        }

        // parallel captures: waves 0-1 own-state halves, waves 2-3 upstream halves
        if (wv < 2) {
            capture8(ring + ((size_t)layer * RD + ((n - 1) & (RD - 1))) * HDIM,
                     (unsigned)(n - 1), ldsOwn[par], lane, wv * 8);
        } else if (wv < 4 && !xphase) {
            const int ul = (layer == 0) ? 3 : layer - 1;
            const unsigned want = (layer == 0) ? (unsigned)(n - 1) : (unsigned)n;
            capture8(ring + ((size_t)ul * RD + (want & (RD - 1))) * HDIM,
                     want, ldsUp[par], lane, (wv - 2) * 8);
        }
        __syncthreads();
        if (threadIdx.x == 0)
            __hip_atomic_store(&prog[blockIdx.x], (unsigned)n, __ATOMIC_RELAXED, __HIP_MEMORY_SCOPE_AGENT);

        // compute this wave's 4 columns
        float a0 = 0.f, a1 = 0.f, a2 = 0.f, a3 = 0.f;
        if (xphase) {
#pragma unroll
            for (int k = 0; k < 4; ++k) {
                float x = xv[k];
                a0 += x * wx0[0][k]; a1 += x * wx0[1][k]; a2 += x * wx0[2][k]; a3 += x * wx0[3][k];
            }
        } else {
#pragma unroll
            for (int k = 0; k < 16; ++k) {
                float x = ldsUp[par][lane + 64 * k];
                a0 += x * A[0][k]; a1 += x * A[1][k]; a2 += x * A[2][k]; a3 += x * A[3][k];
            }
        }
#pragma unroll
        for (int k = 0; k < 16; ++k) {
            float y = ldsOwn[par][lane + 64 * k];
            a0 += y * B[0][k]; a1 += y * B[1][k]; a2 += y * B[2][k]; a3 += y * B[3][k];
        }
        a0 = wsum(a0); a1 = wsum(a1); a2 = wsum(a2); a3 = wsum(a3);
        const bool fph = (layer == 0) && (n > SEQ);
        float r0 = ftanh(a0 + (fph ? bfc[0] : bb[0]));
        float r1 = ftanh(a1 + (fph ? bfc[1] : bb[1]));
        float r2 = ftanh(a2 + (fph ? bfc[2] : bb[2]));
        float r3 = ftanh(a3 + (fph ? bfc[3] : bb[3]));

        // publish tagged results (lanes 0..3 store one column each)
        {
            u64* dst = ring + ((size_t)layer * RD + (n & (RD - 1))) * HDIM + j0;
            if (lane < 4) {
                float v = (lane == 0) ? r0 : (lane == 1) ? r1 : (lane == 2) ? r2 : r3;
                __hip_atomic_store(dst + lane,
                                   ((u64)(unsigned)n << 32) | (u64)__float_as_uint(v),
                                   __ATOMIC_RELAXED, __HIP_MEMORY_SCOPE_AGENT);
            }
        }

        // out row n-2 = ow . h3^{n-1}: operand already in ldsOwn — free handoff
        if (layer == 3 && n >= 2) {
            float a = 0.f;
#pragma unroll
            for (int k = 0; k < 16; ++k) a += ldsOwn[par][lane + 64 * k] * ow[k];
            a = wsum(a);
            if (lane == 0) out[(size_t)(n - 2) * IDIM + jw] = a + obv;
        }
    }

    // epilogue: final output row from h3^{NTOT}
    if (layer == 3) {
        if (wv < 2)
            capture8(ring + ((size_t)3 * RD + (NTOT & (RD - 1))) * HDIM,
                     (unsigned)NTOT, ldsOwn[0], lane, wv * 8);
        __syncthreads();
        float a = 0.f;
#pragma unroll
        for (int k = 0; k < 16; ++k) a += ldsOwn[0][lane + 64 * k] * ow[k];
        a = wsum(a);
        if (lane == 0) out[(size_t)(NTOT - 1) * IDIM + jw] = a + obv;
    }
}

// ---------------- launcher ----------------

extern "C" void kernel_launch(void* const* d_in, const int* in_sizes, int n_in,
                              void* d_out, int out_size, void* d_ws, size_t ws_size,
                              hipStream_t stream) {
    (void)in_sizes; (void)n_in; (void)out_size; (void)ws_size;
    const float* xs   = (const float*)d_in[0];
    const float* Wx0  = (const float*)d_in[1];
    const float* Wh0  = (const float*)d_in[2];
    const float* b0   = (const float*)d_in[3];
    const float* Wxr  = (const float*)d_in[4];
    const float* Whr  = (const float*)d_in[5];
    const float* brst = (const float*)d_in[6];
    const float* outW = (const float*)d_in[7];
    const float* outb = (const float*)d_in[8];
    float* ws  = (float*)d_ws;
    float* out = (float*)d_out;

    k_fuse_w<<<dim3(4, HDIM), dim3(256), 0, stream>>>(outW, Wx0, ws);
    k_fuse_b<<<dim3(4), dim3(256), 0, stream>>>(b0, outb, Wx0, ws);
    k_pack<<<dim3(32, 32, 7), dim3(32, 32), 0, stream>>>(Wh0, Wxr, Whr, ws);
    k_init<<<dim3(64), dim3(512), 0, stream>>>(ws);

    void* args[] = { (void*)&xs, (void*)&Wx0, (void*)&b0, (void*)&brst,
                     (void*)&outW, (void*)&outb, (void*)&ws, (void*)&out };
    hipError_t e = hipLaunchCooperativeKernel((void*)k_scan, dim3(NWG), dim3(TPB),
                                              args, 0, stream);
    if (e != hipSuccess) {
        // fallback: plain launch (128 WGs, <=1 per CU, trivially co-resident)
        k_scan<<<dim3(NWG), dim3(TPB), 0, stream>>>(xs, Wx0, b0, brst, outW, outb, ws, out);
    }
}